// Round 3
// baseline (370.777 us; speedup 1.0000x reference)
//
#include <hip/hip_runtime.h>

// Problem constants
#define T_STEPS 8
#define NROW    42            // C*Dp = 3*14
#define BN      2688          // B*NROW = 64*42
#define H0      256
#define H1      128
#define KFLAT   5376          // NROW*H1

// Row layout is t-minor: m = (b*42 + c*14 + dp)*8 + t, so each thread's
// micro-tile rows are one neuron-group's full time axis and both LIF
// recurrences run in GEMM epilogue registers (bit-identical chain).

// LDS column swizzle: +4 floats every 32 -> stride-8/4 read groups conflict-free
#define SWA(r)  ((r) + ((r) >> 5) * 4)

// ---------------------------------------------------------------------------
// K1: FUSED avg-pool3d -> fc_in -> LIF -> fc_hid -> LIF -> spk_hid.
// 672 blocks x 256 threads, 32 t-minor rows (4 neuron-groups) per block.
// Phase A (verified r1 structure, unchanged): pooled-A staging + Wi tile in
// LDS, 8x4 micro. Phase B redesign: spikes are EXACT 0/1 so spk_in is
// bit-packed into S32[256] (1 KB: bit tm*8+t of word h). The phase-B
// A-operand read is one broadcast ds_read_b32 + bfe/cvt (bit-exact 0.0/1.0),
// and W_hid rows are held in registers (loaded from L2 per 16-k chunk), so
// phase B has NO LDS staging and NO barriers. LDS 45.8->21.5 KB.
// FMA order per output is k-ascending in 16-chunks == r1 exactly.
// ---------------------------------------------------------------------------
__global__ __launch_bounds__(256, 4) void snn_front(
        const float* __restrict__ x,
        const float* __restrict__ Wi,     // W_in  [256][256]
        const float* __restrict__ bi,
        const float* __restrict__ beti,
        const float* __restrict__ thri,
        const float* __restrict__ Wh,     // W_hid [128][256]
        const float* __restrict__ bh,
        const float* __restrict__ beth,
        const float* __restrict__ thrh,
        float* __restrict__ spkh) {       // [21504][128], t-minor rows
    __shared__ float At[16 * 36];         // [k][m]
    __shared__ float Bt[16 * 284];        // [k][n], swizzled cols
    __shared__ unsigned int S32[256];     // packed spk_in: word h, bit g*8+t

    int tid = threadIdx.x;
    int gbase = blockIdx.x * 4;           // 4 neuron-groups per block

    // ---- A staging map: 2 pooled elements per thread per k-chunk ----
    int wp = tid & 15;                    // k-within-chunk == wp
    int q  = tid >> 4;                    // 0..15
    const float* xb0;
    const float* xb1;
    int mloc0 = q * 2, mloc1 = q * 2 + 1; // 0..31
    {
        int g = gbase + (mloc0 >> 3);
        int t = mloc0 & 7;
        int b = g / 42, r = g - b * 42;
        int c = r / 14, dp = r - c * 14;
        xb0 = x + ((long)b * 712704 + (long)c * 237568
                + (long)(t * 29 + 2 * dp) * 1024 + 2 * wp);
    }
    {
        int g = gbase + (mloc1 >> 3);
        int t = mloc1 & 7;
        int b = g / 42, r = g - b * 42;
        int c = r / 14, dp = r - c * 14;
        xb1 = x + ((long)b * 712704 + (long)c * 237568
                + (long)(t * 29 + 2 * dp) * 1024 + 2 * wp);
    }

    // ---- B staging map (phase A): one W_in row per thread, 16 k/chunk ----
    const float* Bp = Wi + (long)tid * 256;
    int bcol = SWA(tid);

    // ---- compute map: 4 row-groups x 64 col-quads ----
    int tm = tid & 3;                     // row-group: rows tm*8 + t
    int tn = tid >> 2;                    // 0..63
    int ca = tm * 8;
    int cb = SWA(tn * 4);

    float acc[8][4] = {};

    for (int k0 = 0; k0 < 256; k0 += 16) {
        int hp = k0 >> 4;
        const float* p0 = xb0 + hp * 64;
        const float* p1 = xb1 + hp * 64;
        float2 a00 = *(const float2*)(p0);
        float2 a01 = *(const float2*)(p0 + 32);
        float2 a02 = *(const float2*)(p0 + 1024);
        float2 a03 = *(const float2*)(p0 + 1056);
        float2 a10 = *(const float2*)(p1);
        float2 a11 = *(const float2*)(p1 + 32);
        float2 a12 = *(const float2*)(p1 + 1024);
        float2 a13 = *(const float2*)(p1 + 1056);
        float4 w0 = *(const float4*)(Bp + k0);
        float4 w1 = *(const float4*)(Bp + k0 + 4);
        float4 w2 = *(const float4*)(Bp + k0 + 8);
        float4 w3 = *(const float4*)(Bp + k0 + 12);
        __syncthreads();
        // pooled values, exact reference add order
        float s0 = a00.x + a00.y + a01.x + a01.y + a02.x + a02.y + a03.x + a03.y;
        float s1 = a10.x + a10.y + a11.x + a11.y + a12.x + a12.y + a13.x + a13.y;
        At[wp * 36 + mloc0] = s0 * 0.125f;
        At[wp * 36 + mloc1] = s1 * 0.125f;
        Bt[ 0 * 284 + bcol] = w0.x; Bt[ 1 * 284 + bcol] = w0.y;
        Bt[ 2 * 284 + bcol] = w0.z; Bt[ 3 * 284 + bcol] = w0.w;
        Bt[ 4 * 284 + bcol] = w1.x; Bt[ 5 * 284 + bcol] = w1.y;
        Bt[ 6 * 284 + bcol] = w1.z; Bt[ 7 * 284 + bcol] = w1.w;
        Bt[ 8 * 284 + bcol] = w2.x; Bt[ 9 * 284 + bcol] = w2.y;
        Bt[10 * 284 + bcol] = w2.z; Bt[11 * 284 + bcol] = w2.w;
        Bt[12 * 284 + bcol] = w3.x; Bt[13 * 284 + bcol] = w3.y;
        Bt[14 * 284 + bcol] = w3.z; Bt[15 * 284 + bcol] = w3.w;
        __syncthreads();
#pragma unroll
        for (int k = 0; k < 16; ++k) {
            float4 av0 = *(const float4*)&At[k * 36 + ca];
            float4 av1 = *(const float4*)&At[k * 36 + ca + 4];
            float4 bv  = *(const float4*)&Bt[k * 284 + cb];
            float am[8] = {av0.x, av0.y, av0.z, av0.w, av1.x, av1.y, av1.z, av1.w};
            float bb[4] = {bv.x, bv.y, bv.z, bv.w};
#pragma unroll
            for (int i = 0; i < 8; ++i)
#pragma unroll
                for (int j = 0; j < 4; ++j)
                    acc[i][j] = fmaf(am[i], bb[j], acc[i][j]);
        }
    }

    // ---- LIF-in epilogue: bit-pack spikes (values exactly 0/1) ----
    unsigned int mybyte[4];
#pragma unroll
    for (int j = 0; j < 4; ++j) {
        int h = tn * 4 + j;
        float be = fminf(fmaxf(beti[h], 0.f), 1.f);
        float th = thri[h];
        float bb = bi[h];
        float mem = 0.f;
        unsigned int byte = 0u;
#pragma unroll
        for (int t = 0; t < T_STEPS; ++t) {
            float cur = acc[t][j] + bb;
            float reset = (mem > th) ? th : 0.f;
            mem = be * mem + cur - reset;
            byte |= ((mem - th) > 0.f) ? (1u << t) : 0u;
        }
        mybyte[j] = byte;
    }
    {
        unsigned char* S8 = (unsigned char*)S32;
#pragma unroll
        for (int j = 0; j < 4; ++j)
            S8[(tn * 4 + j) * 4 + tm] = (unsigned char)mybyte[j];
    }
    __syncthreads();                      // S32 ready; no more barriers below

    // ---- Phase B: cur_hid = spk_in @ W_hid^T, 8x2 micro, barrier-free ----
    const float* wrow0 = Wh + (long)(tn * 2) * 256;
    const float* wrow1 = wrow0 + 256;
    int shift = tm * 8;
    float acc2[8][2] = {};

    for (int k0 = 0; k0 < 256; k0 += 16) {
        float4 w00 = *(const float4*)(wrow0 + k0);
        float4 w01 = *(const float4*)(wrow0 + k0 + 4);
        float4 w02 = *(const float4*)(wrow0 + k0 + 8);
        float4 w03 = *(const float4*)(wrow0 + k0 + 12);
        float4 w10 = *(const float4*)(wrow1 + k0);
        float4 w11 = *(const float4*)(wrow1 + k0 + 4);
        float4 w12 = *(const float4*)(wrow1 + k0 + 8);
        float4 w13 = *(const float4*)(wrow1 + k0 + 12);
        float w0a[16] = {w00.x, w00.y, w00.z, w00.w, w01.x, w01.y, w01.z, w01.w,
                         w02.x, w02.y, w02.z, w02.w, w03.x, w03.y, w03.z, w03.w};
        float w1a[16] = {w10.x, w10.y, w10.z, w10.w, w11.x, w11.y, w11.z, w11.w,
                         w12.x, w12.y, w12.z, w12.w, w13.x, w13.y, w13.z, w13.w};
#pragma unroll
        for (int k = 0; k < 16; ++k) {
            unsigned int sw = S32[k0 + k];          // broadcast read
#pragma unroll
            for (int i = 0; i < 8; ++i) {
                float am = (float)((sw >> (shift + i)) & 1u);  // exact 0/1
                acc2[i][0] = fmaf(am, w0a[k], acc2[i][0]);
                acc2[i][1] = fmaf(am, w1a[k], acc2[i][1]);
            }
        }
    }

    // ---- LIF-hid epilogue + store spk_hid (t-minor rows) ----
#pragma unroll
    for (int j = 0; j < 2; ++j) {
        int h = tn * 2 + j;
        float be = fminf(fmaxf(beth[h], 0.f), 1.f);
        float th = thrh[h];
        float bb = bh[h];
        float mem = 0.f;
#pragma unroll
        for (int t = 0; t < T_STEPS; ++t) {
            float cur = acc2[t][j] + bb;
            float reset = (mem > th) ? th : 0.f;
            mem = be * mem + cur - reset;
            acc2[t][j] = ((mem - th) > 0.f) ? 1.f : 0.f;
        }
    }
    int rbase = blockIdx.x * 32 + tm * 8;
#pragma unroll
    for (int t = 0; t < T_STEPS; ++t) {
        float2 o = {acc2[t][0], acc2[t][1]};
        *(float2*)&spkh[(long)(rbase + t) * 128 + tn * 2] = o;
    }
}

// ---------------------------------------------------------------------------
// K2: FUSED out_gemm + output-LIF. One block per batch b (64 blocks x 512
// threads); two 256-thread groups each own one timestep per round (4 rounds
// cover t=0..7). Per (t,b) the j-partition (j = tid mod 256, ascending), the
// LDS tree pairing (off = 128..1), and the LIF arithmetic are bit-identical
// to the previously passing out_gemm/lif_out pair — the mem>1.0 threshold
// makes reduction-order changes an absmax hazard, so every float op matches.
// ---------------------------------------------------------------------------
__global__ __launch_bounds__(512) void out_fused(const float* __restrict__ spkh,
                                                 const float* __restrict__ W_out,
                                                 const float* __restrict__ b_out,
                                                 const float* __restrict__ beta_out,
                                                 float* __restrict__ out) {
    __shared__ float part[2][256][8];
    __shared__ float curs[8][8];
    int b = blockIdx.x;                      // 0..63
    int grp = threadIdx.x >> 8;              // 0/1
    int tid = threadIdx.x & 255;

    for (int tr = 0; tr < 4; ++tr) {
        int t = tr * 2 + grp;
        float acc[6] = {0.f, 0.f, 0.f, 0.f, 0.f, 0.f};
        for (int j = tid; j < KFLAT; j += 256) {
            int n = j >> 7, h = j & 127;
            float s = spkh[((long)(b * NROW + n) * 8 + t) * 128 + h];
#pragma unroll
            for (int c = 0; c < 6; ++c)
                acc[c] = fmaf(s, W_out[c * KFLAT + j], acc[c]);
        }
#pragma unroll
        for (int c = 0; c < 6; ++c) part[grp][tid][c] = acc[c];
        __syncthreads();
        for (int off = 128; off > 0; off >>= 1) {
            if (tid < off) {
#pragma unroll
                for (int c = 0; c < 6; ++c)
                    part[grp][tid][c] += part[grp][tid + off][c];
            }
            __syncthreads();
        }
        if (tid < 6) curs[t][tid] = part[grp][0][tid] + b_out[tid];
        __syncthreads();                     // curs done; part reusable
    }

    if (threadIdx.x < 6) {                   // LIF chain, identical to lif_out
        int cls = threadIdx.x;
        float be = fminf(fmaxf(beta_out[cls], 0.f), 1.f);
        float mem = 0.f;
#pragma unroll
        for (int t = 0; t < T_STEPS; ++t) {
            float cur = curs[t][cls];
            float reset = (mem > 1.f) ? 1.f : 0.f;
            mem = be * mem + cur - reset;
            out[t * 384 + b * 6 + cls] = ((mem - 1.f) > 0.f) ? 1.f : 0.f;
        }
    }
}

extern "C" void kernel_launch(void* const* d_in, const int* in_sizes, int n_in,
                              void* d_out, int out_size, void* d_ws, size_t ws_size,
                              hipStream_t stream) {
    (void)in_sizes; (void)n_in; (void)out_size; (void)ws_size;
    const float* x        = (const float*)d_in[0];
    const float* W_in     = (const float*)d_in[1];
    const float* b_in     = (const float*)d_in[2];
    const float* W_hid    = (const float*)d_in[3];
    const float* b_hid    = (const float*)d_in[4];
    const float* W_out    = (const float*)d_in[5];
    const float* b_out    = (const float*)d_in[6];
    const float* beta_in  = (const float*)d_in[7];
    const float* thr_in   = (const float*)d_in[8];
    const float* beta_hid = (const float*)d_in[9];
    const float* thr_hid  = (const float*)d_in[10];
    const float* beta_out = (const float*)d_in[11];
    float* out = (float*)d_out;

    float* buf0 = (float*)d_ws;            // spk_hid: 21504*128 floats

    // 1. fused pool + fc_in + LIF + fc_hid + LIF: x -> spk_hid (buf0)
    snn_front<<<672, 256, 0, stream>>>(x, W_in, b_in, beta_in, thr_in,
                                       W_hid, b_hid, beta_hid, thr_hid, buf0);
    // 2. fused out-layer GEMM + LIF -> d_out
    out_fused<<<64, 512, 0, stream>>>(buf0, W_out, b_out, beta_out, out);
}

// Round 4
// 353.150 us; speedup vs baseline: 1.0499x; 1.0499x over previous
//
#include <hip/hip_runtime.h>

// Problem constants
#define T_STEPS 8
#define NROW    42            // C*Dp = 3*14
#define BN      2688          // B*NROW = 64*42
#define H0      256
#define H1      128
#define KFLAT   5376          // NROW*H1

// Row layout is t-minor: m = (b*42 + c*14 + dp)*8 + t, so each thread's
// micro-tile rows are one neuron-group's full time axis and both LIF
// recurrences run in GEMM epilogue registers (bit-identical chain).

// LDS column swizzle: +4 floats every 32 -> stride-8/4 read groups conflict-free
#define SWA(r)  ((r) + ((r) >> 5) * 4)

// ---------------------------------------------------------------------------
// K1: FUSED avg-pool3d -> fc_in -> LIF -> fc_hid -> LIF -> spk_hid.
// 672 blocks x 256 threads, 32 t-minor rows (4 neuron-groups) per block.
// r4 change: phase A is software-pipelined with DOUBLE-BUFFERED LDS
// (At/Bt x2, 41 KB, 3 blocks/CU). Schedule per chunk i:
//   ISSUE(i+1) -> barrier -> FMA(i) -> STAGE(i+1)
// so the ~500-900cy global-load latency hides under the 512-FMA compute of
// the current chunk (per-wave, occupancy-independent), and there is ONE
// barrier per chunk instead of two. Safety: all waves sit between barrier_i
// and barrier_{i+1}; FMA_{i-1} (last reader of the buffer STAGE_{i+1}
// overwrites) precedes barrier_i in program order -> no race.
// FMA order per output is k-ascending in 16-chunks == r1/r3 exactly.
// Phase B (r3-verified): spk_in bit-packed in S32[256] (spikes exact 0/1),
// W_hid rows in registers, broadcast ds_read_b32 + bfe/cvt, no barriers.
// ---------------------------------------------------------------------------
__global__ __launch_bounds__(256, 3) void snn_front(
        const float* __restrict__ x,
        const float* __restrict__ Wi,     // W_in  [256][256]
        const float* __restrict__ bi,
        const float* __restrict__ beti,
        const float* __restrict__ thri,
        const float* __restrict__ Wh,     // W_hid [128][256]
        const float* __restrict__ bh,
        const float* __restrict__ beth,
        const float* __restrict__ thrh,
        float* __restrict__ spkh) {       // [21504][128], t-minor rows
    __shared__ float At[2 * 576];         // [buf][k][m] 16x36
    __shared__ float Bt[2 * 4544];        // [buf][k][n] 16x284, swizzled cols
    __shared__ unsigned int S32[256];     // packed spk_in: word h, bit g*8+t

    int tid = threadIdx.x;
    int gbase = blockIdx.x * 4;           // 4 neuron-groups per block

    // ---- A staging map: 2 pooled elements per thread per k-chunk ----
    int wp = tid & 15;                    // k-within-chunk == wp
    int q  = tid >> 4;                    // 0..15
    const float* xb0;
    const float* xb1;
    int mloc0 = q * 2, mloc1 = q * 2 + 1; // 0..31
    {
        int g = gbase + (mloc0 >> 3);
        int t = mloc0 & 7;
        int b = g / 42, r = g - b * 42;
        int c = r / 14, dp = r - c * 14;
        xb0 = x + ((long)b * 712704 + (long)c * 237568
                + (long)(t * 29 + 2 * dp) * 1024 + 2 * wp);
    }
    {
        int g = gbase + (mloc1 >> 3);
        int t = mloc1 & 7;
        int b = g / 42, r = g - b * 42;
        int c = r / 14, dp = r - c * 14;
        xb1 = x + ((long)b * 712704 + (long)c * 237568
                + (long)(t * 29 + 2 * dp) * 1024 + 2 * wp);
    }

    // ---- B staging map (phase A): one W_in row per thread, 16 k/chunk ----
    const float* Bp = Wi + (long)tid * 256;
    int bcol = SWA(tid);

    // ---- compute map: 4 row-groups x 64 col-quads ----
    int tm = tid & 3;                     // row-group: rows tm*8 + t
    int tn = tid >> 2;                    // 0..63
    int ca = tm * 8;
    int cb = SWA(tn * 4);

    float acc[8][4] = {};
    float2 a00, a01, a02, a03, a10, a11, a12, a13;
    float4 w0, w1, w2, w3;

#define ISSUE(hp) {                                                        \
    const float* p0 = xb0 + (hp) * 64;                                     \
    const float* p1 = xb1 + (hp) * 64;                                     \
    a00 = *(const float2*)(p0);        a01 = *(const float2*)(p0 + 32);    \
    a02 = *(const float2*)(p0 + 1024); a03 = *(const float2*)(p0 + 1056);  \
    a10 = *(const float2*)(p1);        a11 = *(const float2*)(p1 + 32);    \
    a12 = *(const float2*)(p1 + 1024); a13 = *(const float2*)(p1 + 1056);  \
    const float* Bk = Bp + (hp) * 16;                                      \
    w0 = *(const float4*)(Bk);     w1 = *(const float4*)(Bk + 4);          \
    w2 = *(const float4*)(Bk + 8); w3 = *(const float4*)(Bk + 12); }

#define STAGE(bufi) {                                                      \
    float s0 = a00.x + a00.y + a01.x + a01.y + a02.x + a02.y + a03.x + a03.y; \
    float s1 = a10.x + a10.y + a11.x + a11.y + a12.x + a12.y + a13.x + a13.y; \
    float* At_ = At + (bufi) * 576;                                        \
    float* Bt_ = Bt + (bufi) * 4544;                                       \
    At_[wp * 36 + mloc0] = s0 * 0.125f;                                    \
    At_[wp * 36 + mloc1] = s1 * 0.125f;                                    \
    Bt_[ 0 * 284 + bcol] = w0.x; Bt_[ 1 * 284 + bcol] = w0.y;              \
    Bt_[ 2 * 284 + bcol] = w0.z; Bt_[ 3 * 284 + bcol] = w0.w;              \
    Bt_[ 4 * 284 + bcol] = w1.x; Bt_[ 5 * 284 + bcol] = w1.y;              \
    Bt_[ 6 * 284 + bcol] = w1.z; Bt_[ 7 * 284 + bcol] = w1.w;              \
    Bt_[ 8 * 284 + bcol] = w2.x; Bt_[ 9 * 284 + bcol] = w2.y;              \
    Bt_[10 * 284 + bcol] = w2.z; Bt_[11 * 284 + bcol] = w2.w;              \
    Bt_[12 * 284 + bcol] = w3.x; Bt_[13 * 284 + bcol] = w3.y;              \
    Bt_[14 * 284 + bcol] = w3.z; Bt_[15 * 284 + bcol] = w3.w; }

#define FMACHUNK(bufi) {                                                   \
    const float* At_ = At + (bufi) * 576;                                  \
    const float* Bt_ = Bt + (bufi) * 4544;                                 \
    _Pragma("unroll")                                                      \
    for (int k = 0; k < 16; ++k) {                                         \
        float4 av0 = *(const float4*)&At_[k * 36 + ca];                    \
        float4 av1 = *(const float4*)&At_[k * 36 + ca + 4];                \
        float4 bv  = *(const float4*)&Bt_[k * 284 + cb];                   \
        float am[8] = {av0.x, av0.y, av0.z, av0.w,                         \
                       av1.x, av1.y, av1.z, av1.w};                        \
        float bb[4] = {bv.x, bv.y, bv.z, bv.w};                            \
        _Pragma("unroll")                                                  \
        for (int i2 = 0; i2 < 8; ++i2)                                     \
            _Pragma("unroll")                                              \
            for (int j2 = 0; j2 < 4; ++j2)                                 \
                acc[i2][j2] = fmaf(am[i2], bb[j2], acc[i2][j2]);           \
    } }

    ISSUE(0);
    STAGE(0);
#pragma unroll 1
    for (int i = 0; i < 15; ++i) {
        ISSUE(i + 1);                     // in flight across the FMA phase
        __syncthreads();                  // chunk-i buffers ready
        FMACHUNK(i & 1);
        STAGE((i + 1) & 1);               // vmcnt wait lands here, post-FMA
    }
    __syncthreads();
    FMACHUNK(1);                          // chunk 15

#undef ISSUE
#undef STAGE
#undef FMACHUNK

    // ---- LIF-in epilogue: bit-pack spikes (values exactly 0/1) ----
    unsigned int mybyte[4];
#pragma unroll
    for (int j = 0; j < 4; ++j) {
        int h = tn * 4 + j;
        float be = fminf(fmaxf(beti[h], 0.f), 1.f);
        float th = thri[h];
        float bb = bi[h];
        float mem = 0.f;
        unsigned int byte = 0u;
#pragma unroll
        for (int t = 0; t < T_STEPS; ++t) {
            float cur = acc[t][j] + bb;
            float reset = (mem > th) ? th : 0.f;
            mem = be * mem + cur - reset;
            byte |= ((mem - th) > 0.f) ? (1u << t) : 0u;
        }
        mybyte[j] = byte;
    }
    {
        unsigned char* S8 = (unsigned char*)S32;
#pragma unroll
        for (int j = 0; j < 4; ++j)
            S8[(tn * 4 + j) * 4 + tm] = (unsigned char)mybyte[j];
    }
    __syncthreads();                      // S32 ready; no more barriers below

    // ---- Phase B: cur_hid = spk_in @ W_hid^T, 8x2 micro, barrier-free ----
    const float* wrow0 = Wh + (long)(tn * 2) * 256;
    const float* wrow1 = wrow0 + 256;
    int shift = tm * 8;
    float acc2[8][2] = {};

    for (int k0 = 0; k0 < 256; k0 += 16) {
        float4 w00 = *(const float4*)(wrow0 + k0);
        float4 w01 = *(const float4*)(wrow0 + k0 + 4);
        float4 w02 = *(const float4*)(wrow0 + k0 + 8);
        float4 w03 = *(const float4*)(wrow0 + k0 + 12);
        float4 w10 = *(const float4*)(wrow1 + k0);
        float4 w11 = *(const float4*)(wrow1 + k0 + 4);
        float4 w12 = *(const float4*)(wrow1 + k0 + 8);
        float4 w13 = *(const float4*)(wrow1 + k0 + 12);
        float w0a[16] = {w00.x, w00.y, w00.z, w00.w, w01.x, w01.y, w01.z, w01.w,
                         w02.x, w02.y, w02.z, w02.w, w03.x, w03.y, w03.z, w03.w};
        float w1a[16] = {w10.x, w10.y, w10.z, w10.w, w11.x, w11.y, w11.z, w11.w,
                         w12.x, w12.y, w12.z, w12.w, w13.x, w13.y, w13.z, w13.w};
#pragma unroll
        for (int k = 0; k < 16; ++k) {
            unsigned int sw = S32[k0 + k];          // broadcast read
#pragma unroll
            for (int i = 0; i < 8; ++i) {
                float am = (float)((sw >> (shift + i)) & 1u);  // exact 0/1
                acc2[i][0] = fmaf(am, w0a[k], acc2[i][0]);
                acc2[i][1] = fmaf(am, w1a[k], acc2[i][1]);
            }
        }
    }

    // ---- LIF-hid epilogue + store spk_hid (t-minor rows) ----
#pragma unroll
    for (int j = 0; j < 2; ++j) {
        int h = tn * 2 + j;
        float be = fminf(fmaxf(beth[h], 0.f), 1.f);
        float th = thrh[h];
        float bb = bh[h];
        float mem = 0.f;
#pragma unroll
        for (int t = 0; t < T_STEPS; ++t) {
            float cur = acc2[t][j] + bb;
            float reset = (mem > th) ? th : 0.f;
            mem = be * mem + cur - reset;
            acc2[t][j] = ((mem - th) > 0.f) ? 1.f : 0.f;
        }
    }
    int rbase = blockIdx.x * 32 + tm * 8;
#pragma unroll
    for (int t = 0; t < T_STEPS; ++t) {
        float2 o = {acc2[t][0], acc2[t][1]};
        *(float2*)&spkh[(long)(rbase + t) * 128 + tn * 2] = o;
    }
}

// ---------------------------------------------------------------------------
// K3: cur_out[row=(t*64+b)][cls], reading spk_hid in t-minor layout.
// (reverted to the passing 512-block version — the 64-block fused variant
// cost ~28 µs from lost parallelism)
// ---------------------------------------------------------------------------
__global__ __launch_bounds__(256) void out_gemm(const float* __restrict__ spkh,
                                                const float* __restrict__ W_out,
                                                const float* __restrict__ b_out,
                                                float* __restrict__ cur_out) {
    __shared__ float part[256][8];
    int row = blockIdx.x;                    // t*64 + b
    int t = row >> 6, b = row & 63;
    int tid = threadIdx.x;
    float acc[6] = {0.f, 0.f, 0.f, 0.f, 0.f, 0.f};
    for (int j = tid; j < KFLAT; j += 256) {
        int n = j >> 7, h = j & 127;
        float s = spkh[((long)(b * NROW + n) * 8 + t) * 128 + h];
#pragma unroll
        for (int c = 0; c < 6; ++c)
            acc[c] = fmaf(s, W_out[c * KFLAT + j], acc[c]);
    }
#pragma unroll
    for (int c = 0; c < 6; ++c) part[tid][c] = acc[c];
    __syncthreads();
    for (int off = 128; off > 0; off >>= 1) {
        if (tid < off) {
#pragma unroll
            for (int c = 0; c < 6; ++c) part[tid][c] += part[tid + off][c];
        }
        __syncthreads();
    }
    if (tid < 6) cur_out[row * 6 + tid] = part[0][tid] + b_out[tid];
}

// ---------------------------------------------------------------------------
// K4: output-layer LIF (threshold 1.0), writes spikes (8,64,6) to d_out
// ---------------------------------------------------------------------------
__global__ void lif_out_kernel(const float* __restrict__ cur_out,
                               const float* __restrict__ beta_out,
                               float* __restrict__ out) {
    int j = threadIdx.x;                     // < 384, j = b*6 + cls
    if (j >= 384) return;
    int cls = j % 6;
    float be = fminf(fmaxf(beta_out[cls], 0.f), 1.f);
    float mem = 0.f;
#pragma unroll
    for (int t = 0; t < T_STEPS; ++t) {
        float cur = cur_out[t * 384 + j];
        float reset = (mem > 1.f) ? 1.f : 0.f;
        mem = be * mem + cur - reset;
        out[t * 384 + j] = ((mem - 1.f) > 0.f) ? 1.f : 0.f;
    }
}

extern "C" void kernel_launch(void* const* d_in, const int* in_sizes, int n_in,
                              void* d_out, int out_size, void* d_ws, size_t ws_size,
                              hipStream_t stream) {
    (void)in_sizes; (void)n_in; (void)out_size; (void)ws_size;
    const float* x        = (const float*)d_in[0];
    const float* W_in     = (const float*)d_in[1];
    const float* b_in     = (const float*)d_in[2];
    const float* W_hid    = (const float*)d_in[3];
    const float* b_hid    = (const float*)d_in[4];
    const float* W_out    = (const float*)d_in[5];
    const float* b_out    = (const float*)d_in[6];
    const float* beta_in  = (const float*)d_in[7];
    const float* thr_in   = (const float*)d_in[8];
    const float* beta_hid = (const float*)d_in[9];
    const float* thr_hid  = (const float*)d_in[10];
    const float* beta_out = (const float*)d_in[11];
    float* out = (float*)d_out;

    float* buf0 = (float*)d_ws;            // spk_hid: 21504*128 floats
    float* curo = buf0 + 2752512;          // 3,072 floats

    // 1. fused pool + fc_in + LIF + fc_hid + LIF: x -> spk_hid (buf0)
    snn_front<<<672, 256, 0, stream>>>(x, W_in, b_in, beta_in, thr_in,
                                       W_hid, b_hid, beta_hid, thr_hid, buf0);
    // 2. cur_out_all: (t,b) rows x 5376 -> 6
    out_gemm<<<512, 256, 0, stream>>>(buf0, W_out, b_out, curo);
    // 3. output LIF -> d_out
    lif_out_kernel<<<1, 384, 0, stream>>>(curo, beta_out, out);
}